// Round 3
// baseline (208.687 us; speedup 1.0000x reference)
//
#include <hip/hip_runtime.h>

// Shapes (fixed):
//   prev/next: [8, 32, 48, 48, 48] f32
//   phi:       [8, 1, 96, 96, 96] f32
//   stream:    [8, 3, 96, 96, 96] f32
// Outputs concatenated in d_out (f32): corr [8,27,48^3], vel/vel_phi/vel_stream [8,3,94^3]
//
// FUSED single dispatch: blocks [0,1728) = corr phase, [1728, 14706) = vel
// phase. 1728 % 8 == 0 so both segments keep their XCD swizzle alignment
// (local bid&7 == physical XCD slot). Fusion makes the dispatch large enough
// to appear in rocprof top-5 (fills are ~190 us) -> first real counter read.

typedef float f2 __attribute__((ext_vector_type(2)));

constexpr int CB = 8, CC = 32, CX = 48, CY = 48, CZ = 48;
constexpr int H = 96, O = 94;

constexpr int CORR_NWG = (CB * CX * CY * (CZ / 2)) / 256;    // 1728
constexpr int VEL_TOTAL = CB * O * O * (O / 2);              // 3,322,336
constexpr int VEL_NWG = (VEL_TOTAL + 255) / 256;             // 12978

__device__ __forceinline__ void corr_body(
    int bid, const float* __restrict__ prev, const float* __restrict__ nxt,
    float* __restrict__ corr)
{
    constexpr int Z2 = CZ / 2;                       // 24
    int swz = (bid & 7) * (CORR_NWG / 8) + (bid >> 3);  // XCD k -> batch b = k
    int idx = swz * 256 + (int)threadIdx.x;
    int z2 = idx % Z2; int r = idx / Z2;
    int y = r % CY; r /= CY;
    int x = r % CX; int b = r / CX;

    const int plane = CY * CZ;                       // 2304
    const int cstr  = CX * plane;                    // 110592
    const size_t bbase = (size_t)b * CC * cstr;

    const float* pp = prev + bbase + (size_t)x * plane + (size_t)y * CZ + z2 * 2;

    const float* tpx[3];
    bool okx[3], oky[3];
#pragma unroll
    for (int d = 0; d < 3; ++d) {
        int xx = x + d - 1;
        okx[d] = (unsigned)xx < (unsigned)CX;
        tpx[d] = nxt + bbase + (size_t)(okx[d] ? xx : x) * plane
                             + (size_t)y * CZ + z2 * 2;
        int yy = y + d - 1;
        oky[d] = (unsigned)yy < (unsigned)CY;
    }
    bool okj[9];
#pragma unroll
    for (int a = 0; a < 3; ++a)
#pragma unroll
        for (int dyy = 0; dyy < 3; ++dyy) okj[a * 3 + dyy] = okx[a] && oky[dyy];

    f2 acc[9];
#pragma unroll
    for (int jj = 0; jj < 9; ++jj) acc[jj] = f2{0.f, 0.f};

#pragma unroll 2
    for (int c = 0; c < CC; ++c) {
        f2 pv = *reinterpret_cast<const f2*>(pp);
#pragma unroll
        for (int a = 0; a < 3; ++a) {
#pragma unroll
            for (int dyy = 0; dyy < 3; ++dyy) {
                const int jj = a * 3 + dyy;
                if (okj[jj]) {
                    f2 nv = *reinterpret_cast<const f2*>(tpx[a] + (dyy - 1) * CZ);
                    acc[jj] += pv * nv;
                }
            }
            tpx[a] += cstr;
        }
        pp += cstr;
    }

    const size_t obase = (size_t)b * 27 * cstr + (size_t)x * plane
                       + (size_t)y * CZ + z2 * 2;
    const float s = 1.0f / 32.0f;
#pragma unroll
    for (int jj = 0; jj < 9; ++jj) {
        f2 v = acc[jj] * s;
        f2 gm = v; if (z2 == Z2 - 1) gm.y = 0.f;     // k=-1: zero z==47
        f2 gp = v; if (z2 == 0)      gp.x = 0.f;     // k=+1: zero z==0
        __builtin_nontemporal_store(gm, (f2*)(corr + obase + (size_t)jj * cstr));
        __builtin_nontemporal_store(v,  (f2*)(corr + obase + (size_t)(9 + jj) * cstr));
        __builtin_nontemporal_store(gp, (f2*)(corr + obase + (size_t)(18 + jj) * cstr));
    }
}

__device__ __forceinline__ void vel_body(
    int bid, const float* __restrict__ phi, const float* __restrict__ stm,
    float* __restrict__ vel, float* __restrict__ vphi, float* __restrict__ vstr)
{
    constexpr int TT = O / 2;                        // 47
    const int q = VEL_NWG >> 3, rr = VEL_NWG & 7;    // 1622, 2
    int xcd = bid & 7, g = bid >> 3;
    int swz = (xcd < rr) ? (xcd * (q + 1) + g) : (rr * (q + 1) + (xcd - rr) * q + g);
    int idx = swz * 256 + (int)threadIdx.x;
    if (idx >= VEL_TOTAL) return;
    int tt = idx % TT; int r2 = idx / TT;
    int j = r2 % O; r2 /= O;
    int i = r2 % O; int b = r2 / O;
    const int t = tt * 2;

    const int hp = H * H;                            // 9216
    const size_t hc = (size_t)H * hp;
    const float* ph = phi + (size_t)b * hc;
    const float* s0 = stm + (size_t)b * 3 * hc;
    const float* s1 = s0 + hc;
    const float* s2 = s1 + hc;

#define R(A, B_) ((size_t)(A) * hp + (size_t)(B_) * H + t)

    // ---- phi taps ----
    const float* p11 = ph + R(i + 1, j + 1);
    f2 p11a = *(const f2*)p11;           // t, t+1
    f2 p11b = *(const f2*)(p11 + 2);     // t+2, t+3
    float p12_1 = ph[R(i + 1, j + 2) + 1], p12_2 = ph[R(i + 1, j + 2) + 2];
    float p10_1 = ph[R(i + 1, j)     + 1], p10_2 = ph[R(i + 1, j)     + 2];
    float p21_1 = ph[R(i + 2, j + 1) + 1], p21_2 = ph[R(i + 2, j + 1) + 2];
    float p01_1 = ph[R(i,     j + 1) + 1], p01_2 = ph[R(i,     j + 1) + 2];

    float pc0 = p11a.y, pc1 = p11b.x;
    float mup0 = ((p11b.x - pc0) + (pc0 - p11a.x)) * 0.5f;
    float mup1 = ((p11b.y - pc1) + (pc1 - p11a.y)) * 0.5f;
    float mvp0 = ((p12_1 - pc0) + (pc0 - p10_1)) * 0.5f;
    float mvp1 = ((p12_2 - pc1) + (pc1 - p10_2)) * 0.5f;
    float mwp0 = ((p21_1 - pc0) + (pc0 - p01_1)) * 0.5f;
    float mwp1 = ((p21_2 - pc1) + (pc1 - p01_2)) * 0.5f;

    // ---- stream taps ----
    const float* q1_11 = s1 + R(i + 1, j + 1);
    f2 s1_11a = *(const f2*)q1_11;  f2 s1_11b = *(const f2*)(q1_11 + 2);
    const float* q1_21 = s1 + R(i + 2, j + 1);
    f2 s1_21a = *(const f2*)q1_21;  float s1_21_2 = q1_21[2];
    const float* q1_01 = s1 + R(i, j + 1);
    float s1_01_1 = q1_01[1];       f2 s1_01b = *(const f2*)(q1_01 + 2);

    const float* q0_11 = s0 + R(i + 1, j + 1);
    f2 s0_11a = *(const f2*)q0_11;  f2 s0_11b = *(const f2*)(q0_11 + 2);
    const float* q0_12 = s0 + R(i + 1, j + 2);
    f2 s0_12a = *(const f2*)q0_12;  float s0_12_2 = q0_12[2];
    const float* q0_10 = s0 + R(i + 1, j);
    float s0_10_1 = q0_10[1];       f2 s0_10b = *(const f2*)(q0_10 + 2);

    float s2_21_1 = s2[R(i + 2, j + 1) + 1], s2_21_2 = s2[R(i + 2, j + 1) + 2];
    float s2_11_1 = s2[R(i + 1, j + 1) + 1], s2_11_2 = s2[R(i + 1, j + 1) + 2];
    float s2_20_1 = s2[R(i + 2, j)     + 1], s2_20_2 = s2[R(i + 2, j)     + 2];
    float s2_10_1 = s2[R(i + 1, j)     + 1], s2_10_2 = s2[R(i + 1, j)     + 2];
    float s2_12_1 = s2[R(i + 1, j + 2) + 1], s2_12_2 = s2[R(i + 1, j + 2) + 2];
    float s2_02_1 = s2[R(i,     j + 2) + 1], s2_02_2 = s2[R(i,     j + 2) + 2];
    float s2_01_1 = s2[R(i,     j + 1) + 1], s2_01_2 = s2[R(i,     j + 1) + 2];
#undef R

    // u = d_x s1 - d_y s0 ; mu = (u(t+1)+u(t))/2
    float u0 = (s1_21a.x - s1_11a.x) - (s0_12a.x - s0_11a.x);
    float u1 = (s1_21a.y - s1_11a.y) - (s0_12a.y - s0_11a.y);
    float u2 = (s1_21_2  - s1_11b.x) - (s0_12_2  - s0_11b.x);
    float mus0 = (u1 + u0) * 0.5f;
    float mus1 = (u2 + u1) * 0.5f;

    // v = d_t s0 - d_x s2 ; mv = (v(j+1)+v(j))/2
    float v1_0 = (s0_11b.x - s0_11a.y) - (s2_21_1 - s2_11_1);
    float v0_0 = (s0_10b.x - s0_10_1)  - (s2_20_1 - s2_10_1);
    float mvs0 = (v1_0 + v0_0) * 0.5f;
    float v1_1 = (s0_11b.y - s0_11b.x) - (s2_21_2 - s2_11_2);
    float v0_1 = (s0_10b.y - s0_10b.x) - (s2_20_2 - s2_10_2);
    float mvs1 = (v1_1 + v0_1) * 0.5f;

    // w = d_y s2 - d_t s1 ; mw = (w(i+1)+w(i))/2
    float w1_0 = (s2_12_1 - s2_11_1) - (s1_11b.x - s1_11a.y);
    float w0_0 = (s2_02_1 - s2_01_1) - (s1_01b.x - s1_01_1);
    float mws0 = (w1_0 + w0_0) * 0.5f;
    float w1_1 = (s2_12_2 - s2_11_2) - (s1_11b.y - s1_11b.x);
    float w0_1 = (s2_02_2 - s2_01_2) - (s1_01b.y - s1_01b.x);
    float mws1 = (w1_1 + w0_1) * 0.5f;

    const size_t oc = (size_t)O * O * O;
    const size_t o  = ((size_t)i * O + j) * O + t;
    const size_t b3 = (size_t)b * 3;
    __builtin_nontemporal_store(f2{mup0, mup1}, (f2*)(vphi + (b3 + 0) * oc + o));
    __builtin_nontemporal_store(f2{mvp0, mvp1}, (f2*)(vphi + (b3 + 1) * oc + o));
    __builtin_nontemporal_store(f2{mwp0, mwp1}, (f2*)(vphi + (b3 + 2) * oc + o));
    __builtin_nontemporal_store(f2{mus0, mus1}, (f2*)(vstr + (b3 + 0) * oc + o));
    __builtin_nontemporal_store(f2{mvs0, mvs1}, (f2*)(vstr + (b3 + 1) * oc + o));
    __builtin_nontemporal_store(f2{mws0, mws1}, (f2*)(vstr + (b3 + 2) * oc + o));
    __builtin_nontemporal_store(f2{mup0 + mus0, mup1 + mus1}, (f2*)(vel + (b3 + 0) * oc + o));
    __builtin_nontemporal_store(f2{mvp0 + mvs0, mvp1 + mvs1}, (f2*)(vel + (b3 + 1) * oc + o));
    __builtin_nontemporal_store(f2{mwp0 + mws0, mwp1 + mws1}, (f2*)(vel + (b3 + 2) * oc + o));
}

__global__ __launch_bounds__(256) void fused_kernel(
    const float* __restrict__ prev, const float* __restrict__ nxt,
    const float* __restrict__ phi, const float* __restrict__ stm,
    float* __restrict__ corr, float* __restrict__ vel,
    float* __restrict__ vphi, float* __restrict__ vstr)
{
    int bid = blockIdx.x;
    if (bid < CORR_NWG) {
        corr_body(bid, prev, nxt, corr);
    } else {
        vel_body(bid - CORR_NWG, phi, stm, vel, vphi, vstr);
    }
}

extern "C" void kernel_launch(void* const* d_in, const int* in_sizes, int n_in,
                              void* d_out, int out_size, void* d_ws, size_t ws_size,
                              hipStream_t stream)
{
    const float* prev = (const float*)d_in[0];
    const float* nxt  = (const float*)d_in[1];
    const float* phi  = (const float*)d_in[2];
    const float* stm  = (const float*)d_in[3];

    float* out = (float*)d_out;
    const size_t corr_sz = (size_t)CB * 27 * CX * CY * CZ;   // 23,887,872
    const size_t vel_sz  = (size_t)CB * 3 * O * O * O;       // 19,934,016
    float* corr = out;
    float* vel  = out + corr_sz;
    float* vphi = vel + vel_sz;
    float* vstr = vphi + vel_sz;

    fused_kernel<<<CORR_NWG + VEL_NWG, 256, 0, stream>>>(
        prev, nxt, phi, stm, corr, vel, vphi, vstr);
}